// Round 4
// baseline (44.724 us; speedup 1.0000x reference)
//
#include <hip/hip_runtime.h>
#include <math.h>

#define N2V 32
#define BLOCK 256
#define APT 8                 // a-values per thread
#define CHUNK 2048            // 64 b-values x 32 a-values per block

__global__ __launch_bounds__(BLOCK) void s4d_vand_kernel(
    const float* __restrict__ C,          // (H, N2, 2)
    const float* __restrict__ log_dt,     // (H,)
    const float* __restrict__ log_A_real, // (H, N2)
    const float* __restrict__ A_imag,     // (H, N2)
    float* __restrict__ K,                // (H, L)
    int L, int chunks_per_h)
{
    __shared__ float4 sC[N2V];            // (x, y, 2*Ceff_r, 2*Ceff_i)
    __shared__ float2 sP[N2V][64];        // P[n][b] = 2*Ceff_n * r_n^b
    __shared__ float4 sQ[N2V][16];        // (Re r^(c+128k), -Im, Re r^(c+128k+64), -Im)

    const int h     = blockIdx.x / chunks_per_h;
    const int chunk = (blockIdx.x % chunks_per_h) * CHUNK;
    const int t     = threadIdx.x;

    // ---- stage 1: per-n constants (accurate math, one-time) ----
    if (t < N2V) {
        const int n = t;
        const float dt = expf(log_dt[h]);
        const float ar = -expf(log_A_real[h * N2V + n]);  // Re(A)
        const float ai = A_imag[h * N2V + n];             // Im(A)
        const float x = ar * dt;                          // Re(dtA)
        const float y = ai * dt;                          // Im(dtA)
        float sn, cs;
        sincosf(y, &sn, &cs);
        const float e  = expf(x);
        const float wr = e * cs - 1.0f;                   // w = exp(dtA)-1
        const float wi = e * sn;
        const float inv = 1.0f / (ar * ar + ai * ai);     // w/A = w*conj(A)/|A|^2
        const float dr = (wr * ar + wi * ai) * inv;
        const float di = (wi * ar - wr * ai) * inv;
        const float cr = C[(h * N2V + n) * 2 + 0];
        const float ci = C[(h * N2V + n) * 2 + 1];
        sC[n] = make_float4(x, y,
                            2.0f * (cr * dr - ci * di),
                            2.0f * (cr * di + ci * dr));
    }
    __syncthreads();

    // ---- stage 2a: build P table (2048 entries, 8 per thread) ----
#pragma unroll
    for (int i = 0; i < 8; ++i) {
        const int e = t + i * BLOCK;          // 0..2047
        const int n = e >> 6;
        const int b = e & 63;
        const float4 c = sC[n];
        const float fb = (float)b;
        float sn, cs;
        __sincosf(c.y * fb, &sn, &cs);
        const float ex = __expf(c.x * fb);
        sP[n][b] = make_float2(ex * (c.z * cs - c.w * sn),
                               ex * (c.z * sn + c.w * cs));
    }
    // ---- stage 2b: build Q table (512 float4 entries, 2 per thread) ----
#pragma unroll
    for (int i = 0; i < 2; ++i) {
        const int e = t + i * BLOCK;          // 0..511
        const int n = e >> 4;
        const int k = e & 15;
        const float4 c = sC[n];
        const float l1 = (float)(chunk + 128 * k);
        const float l2 = l1 + 64.0f;
        float sn1, cs1, sn2, cs2;
        __sincosf(c.y * l1, &sn1, &cs1);
        __sincosf(c.y * l2, &sn2, &cs2);
        const float e1 = __expf(c.x * l1);
        const float e2 = __expf(c.x * l2);
        sQ[n][k] = make_float4(e1 * cs1, -e1 * sn1, e2 * cs2, -e2 * sn2);
    }
    __syncthreads();

    // ---- main: pure-FMA reduction over n ----
    const int b  = t & 63;                    // lane -> b (contiguous LDS + stores)
    const int w  = t >> 6;                    // wave id -> a-group
    const int k0 = w * 4;                     // 4 float4 = 8 a-values

    float acc[APT];
#pragma unroll
    for (int j = 0; j < APT; ++j) acc[j] = 0.0f;

#pragma unroll
    for (int n = 0; n < N2V; ++n) {
        const float2 p  = sP[n][b];           // per-lane b64, conflict-free
        const float4 q0 = sQ[n][k0 + 0];      // wave-uniform broadcast b128
        const float4 q1 = sQ[n][k0 + 1];
        const float4 q2 = sQ[n][k0 + 2];
        const float4 q3 = sQ[n][k0 + 3];
        acc[0] = fmaf(p.x, q0.x, fmaf(p.y, q0.y, acc[0]));
        acc[1] = fmaf(p.x, q0.z, fmaf(p.y, q0.w, acc[1]));
        acc[2] = fmaf(p.x, q1.x, fmaf(p.y, q1.y, acc[2]));
        acc[3] = fmaf(p.x, q1.z, fmaf(p.y, q1.w, acc[3]));
        acc[4] = fmaf(p.x, q2.x, fmaf(p.y, q2.y, acc[4]));
        acc[5] = fmaf(p.x, q2.z, fmaf(p.y, q2.w, acc[5]));
        acc[6] = fmaf(p.x, q3.x, fmaf(p.y, q3.y, acc[6]));
        acc[7] = fmaf(p.x, q3.z, fmaf(p.y, q3.w, acc[7]));
    }

    float* out = K + (size_t)h * L + chunk + b;
#pragma unroll
    for (int j = 0; j < APT; ++j) {
        const int a = w * APT + j;
        const int l = chunk + 64 * a + b;
        if (l < L) out[64 * a] = acc[j];      // coalesced 256B per wave-store
    }
}

extern "C" void kernel_launch(void* const* d_in, const int* in_sizes, int n_in,
                              void* d_out, int out_size, void* d_ws, size_t ws_size,
                              hipStream_t stream) {
    // inputs: [0]=L (scalar), [1]=C (H,N2,2), [2]=log_dt (H,),
    //         [3]=log_A_real (H,N2), [4]=A_imag (H,N2)
    const float* C          = (const float*)d_in[1];
    const float* log_dt     = (const float*)d_in[2];
    const float* log_A_real = (const float*)d_in[3];
    const float* A_imag     = (const float*)d_in[4];
    float* K = (float*)d_out;

    const int H = in_sizes[2];            // log_dt has H elements
    const int L = out_size / H;           // output is (H, L)
    const int chunks_per_h = (L + CHUNK - 1) / CHUNK;

    dim3 grid(H * chunks_per_h);
    dim3 block(BLOCK);
    s4d_vand_kernel<<<grid, block, 0, stream>>>(C, log_dt, log_A_real, A_imag,
                                                K, L, chunks_per_h);
}

// Round 5
// 14.859 us; speedup vs baseline: 3.0099x; 3.0099x over previous
//
#include <hip/hip_runtime.h>
#include <math.h>

#define N2V 32
#define BLOCK 256
#define APT 8                 // a-values per thread
#define CHUNK 2048            // 64 b-values x 32 a-values per block

__global__ __launch_bounds__(BLOCK) void s4d_vand_kernel(
    const float* __restrict__ C,          // (H, N2, 2)
    const float* __restrict__ log_dt,     // (H,)
    const float* __restrict__ log_A_real, // (H, N2)
    const float* __restrict__ A_imag,     // (H, N2)
    float* __restrict__ K,                // (H, L)
    int L, int chunks_per_h)
{
    __shared__ float4 sC[N2V];            // (x, y, 2*Ceff_r, 2*Ceff_i)
    __shared__ float2 sP[N2V][64];        // P[n][b] = 2*Ceff_n * r_n^b
    __shared__ float4 sQ[N2V][16];        // (Re r^(c+128k), -Im, Re r^(c+128k+64), -Im)

    const int h     = blockIdx.x / chunks_per_h;
    const int chunk = (blockIdx.x % chunks_per_h) * CHUNK;
    const int t     = threadIdx.x;

    // ---- stage 1: per-n constants (accurate math, one-time) ----
    if (t < N2V) {
        const int n = t;
        const float dt = expf(log_dt[h]);
        const float ar = -expf(log_A_real[h * N2V + n]);  // Re(A)
        const float ai = A_imag[h * N2V + n];             // Im(A)
        const float x = ar * dt;                          // Re(dtA)
        const float y = ai * dt;                          // Im(dtA)
        float sn, cs;
        sincosf(y, &sn, &cs);
        const float e  = expf(x);
        const float wr = e * cs - 1.0f;                   // w = exp(dtA)-1
        const float wi = e * sn;
        const float inv = 1.0f / (ar * ar + ai * ai);     // w/A = w*conj(A)/|A|^2
        const float dr = (wr * ar + wi * ai) * inv;
        const float di = (wi * ar - wr * ai) * inv;
        const float cr = C[(h * N2V + n) * 2 + 0];
        const float ci = C[(h * N2V + n) * 2 + 1];
        sC[n] = make_float4(x, y,
                            2.0f * (cr * dr - ci * di),
                            2.0f * (cr * di + ci * dr));
    }
    __syncthreads();

    // ---- stage 2a: build P table (2048 entries, 8 per thread) ----
#pragma unroll
    for (int i = 0; i < 8; ++i) {
        const int e = t + i * BLOCK;          // 0..2047
        const int n = e >> 6;
        const int b = e & 63;
        const float4 c = sC[n];
        const float fb = (float)b;
        float sn, cs;
        __sincosf(c.y * fb, &sn, &cs);
        const float ex = __expf(c.x * fb);
        sP[n][b] = make_float2(ex * (c.z * cs - c.w * sn),
                               ex * (c.z * sn + c.w * cs));
    }
    // ---- stage 2b: build Q table (512 float4 entries, 2 per thread) ----
#pragma unroll
    for (int i = 0; i < 2; ++i) {
        const int e = t + i * BLOCK;          // 0..511
        const int n = e >> 4;
        const int k = e & 15;
        const float4 c = sC[n];
        const float l1 = (float)(chunk + 128 * k);
        const float l2 = l1 + 64.0f;
        float sn1, cs1, sn2, cs2;
        __sincosf(c.y * l1, &sn1, &cs1);
        __sincosf(c.y * l2, &sn2, &cs2);
        const float e1 = __expf(c.x * l1);
        const float e2 = __expf(c.x * l2);
        sQ[n][k] = make_float4(e1 * cs1, -e1 * sn1, e2 * cs2, -e2 * sn2);
    }
    __syncthreads();

    // ---- main: pure-FMA reduction over n ----
    const int b  = t & 63;                    // lane -> b (contiguous LDS + stores)
    const int w  = t >> 6;                    // wave id -> a-group
    const int k0 = w * 4;                     // 4 float4 = 8 a-values

    float acc[APT];
#pragma unroll
    for (int j = 0; j < APT; ++j) acc[j] = 0.0f;

    // unroll 2 ONLY: full unroll hoists 32x18 LDS-loaded floats -> VGPR=256
    // + scratch spills (round-4 profile: FETCH 9.5 MB, occupancy 9%).
#pragma unroll 2
    for (int n = 0; n < N2V; ++n) {
        const float2 p  = sP[n][b];           // per-lane b64, conflict-free
        const float4 q0 = sQ[n][k0 + 0];      // wave-uniform broadcast b128
        const float4 q1 = sQ[n][k0 + 1];
        const float4 q2 = sQ[n][k0 + 2];
        const float4 q3 = sQ[n][k0 + 3];
        acc[0] = fmaf(p.x, q0.x, fmaf(p.y, q0.y, acc[0]));
        acc[1] = fmaf(p.x, q0.z, fmaf(p.y, q0.w, acc[1]));
        acc[2] = fmaf(p.x, q1.x, fmaf(p.y, q1.y, acc[2]));
        acc[3] = fmaf(p.x, q1.z, fmaf(p.y, q1.w, acc[3]));
        acc[4] = fmaf(p.x, q2.x, fmaf(p.y, q2.y, acc[4]));
        acc[5] = fmaf(p.x, q2.z, fmaf(p.y, q2.w, acc[5]));
        acc[6] = fmaf(p.x, q3.x, fmaf(p.y, q3.y, acc[6]));
        acc[7] = fmaf(p.x, q3.z, fmaf(p.y, q3.w, acc[7]));
    }

    float* out = K + (size_t)h * L + chunk + b;
#pragma unroll
    for (int j = 0; j < APT; ++j) {
        const int a = w * APT + j;
        const int l = chunk + 64 * a + b;
        if (l < L) out[64 * a] = acc[j];      // coalesced 256B per wave-store
    }
}

extern "C" void kernel_launch(void* const* d_in, const int* in_sizes, int n_in,
                              void* d_out, int out_size, void* d_ws, size_t ws_size,
                              hipStream_t stream) {
    // inputs: [0]=L (scalar), [1]=C (H,N2,2), [2]=log_dt (H,),
    //         [3]=log_A_real (H,N2), [4]=A_imag (H,N2)
    const float* C          = (const float*)d_in[1];
    const float* log_dt     = (const float*)d_in[2];
    const float* log_A_real = (const float*)d_in[3];
    const float* A_imag     = (const float*)d_in[4];
    float* K = (float*)d_out;

    const int H = in_sizes[2];            // log_dt has H elements
    const int L = out_size / H;           // output is (H, L)
    const int chunks_per_h = (L + CHUNK - 1) / CHUNK;

    dim3 grid(H * chunks_per_h);
    dim3 block(BLOCK);
    s4d_vand_kernel<<<grid, block, 0, stream>>>(C, log_dt, log_A_real, A_imag,
                                                K, L, chunks_per_h);
}

// Round 6
// 13.865 us; speedup vs baseline: 3.2256x; 1.0717x over previous
//
#include <hip/hip_runtime.h>
#include <math.h>

#define N2V 32
#define BLOCK 256
#define APT 8                 // a-values per thread
#define CHUNK 2048            // 64 b-values x 32 a-values per block

typedef float v2f __attribute__((ext_vector_type(2)));

__global__ __launch_bounds__(BLOCK) void s4d_vand_kernel(
    const float* __restrict__ C,          // (H, N2, 2)
    const float* __restrict__ log_dt,     // (H,)
    const float* __restrict__ log_A_real, // (H, N2)
    const float* __restrict__ A_imag,     // (H, N2)
    float* __restrict__ K,                // (H, L)
    int L, int chunks_per_h)
{
    __shared__ float4 sC[N2V];            // (x, y, 2*Ceff_r, 2*Ceff_i)
    __shared__ float2 sP[N2V][64];        // P[n][b] = 2*Ceff_n * r_n^b
    __shared__ float4 sQre[N2V][8];       // Re r^(chunk+64a), a = 4k..4k+3
    __shared__ float4 sQim[N2V][8];       // -Im r^(chunk+64a)

    const int h     = blockIdx.x / chunks_per_h;
    const int chunk = (blockIdx.x % chunks_per_h) * CHUNK;
    const int t     = threadIdx.x;

    // ---- stage 1: per-n constants (accurate math, one-time) ----
    if (t < N2V) {
        const int n = t;
        const float dt = expf(log_dt[h]);
        const float ar = -expf(log_A_real[h * N2V + n]);  // Re(A)
        const float ai = A_imag[h * N2V + n];             // Im(A)
        const float x = ar * dt;                          // Re(dtA)
        const float y = ai * dt;                          // Im(dtA)
        float sn, cs;
        sincosf(y, &sn, &cs);
        const float e  = expf(x);
        const float wr = e * cs - 1.0f;                   // w = exp(dtA)-1
        const float wi = e * sn;
        const float inv = 1.0f / (ar * ar + ai * ai);     // w/A = w*conj(A)/|A|^2
        const float dr = (wr * ar + wi * ai) * inv;
        const float di = (wi * ar - wr * ai) * inv;
        const float cr = C[(h * N2V + n) * 2 + 0];
        const float ci = C[(h * N2V + n) * 2 + 1];
        sC[n] = make_float4(x, y,
                            2.0f * (cr * dr - ci * di),
                            2.0f * (cr * di + ci * dr));
    }
    __syncthreads();

    // ---- stage 2a: build P table (2048 entries, 8 per thread) ----
#pragma unroll
    for (int i = 0; i < 8; ++i) {
        const int e = t + i * BLOCK;          // 0..2047
        const int n = e >> 6;
        const int b = e & 63;
        const float4 c = sC[n];
        const float fb = (float)b;
        float sn, cs;
        __sincosf(c.y * fb, &sn, &cs);
        const float ex = __expf(c.x * fb);
        sP[n][b] = make_float2(ex * (c.z * cs - c.w * sn),
                               ex * (c.z * sn + c.w * cs));
    }
    // ---- stage 2b: build Q tables (256 float4-pairs, 1 per thread) ----
    {
        const int n = t >> 3;                 // 0..31
        const int k = t & 7;                  // 0..7 -> a = 4k..4k+3
        const float4 c = sC[n];
        float re[4], im[4];
#pragma unroll
        for (int j = 0; j < 4; ++j) {
            const float fl = (float)(chunk + 64 * (4 * k + j));
            float sn, cs;
            __sincosf(c.y * fl, &sn, &cs);
            const float ex = __expf(c.x * fl);
            re[j] = ex * cs;
            im[j] = -ex * sn;
        }
        sQre[n][k] = make_float4(re[0], re[1], re[2], re[3]);
        sQim[n][k] = make_float4(im[0], im[1], im[2], im[3]);
    }
    __syncthreads();

    // ---- main: packed-FMA reduction over n ----
    const int b  = t & 63;                    // lane -> b (contiguous LDS + stores)
    const int w  = t >> 6;                    // wave id -> a-group (a = 8w..8w+7)

    v2f acc[4];
#pragma unroll
    for (int j = 0; j < 4; ++j) acc[j] = (v2f){0.0f, 0.0f};

    // unroll 2 only: full unroll blew VGPR to 256 + spills in round 4.
#pragma unroll 2
    for (int n = 0; n < N2V; ++n) {
        const float2 p   = sP[n][b];          // per-lane b64, conflict-free
        const float4 re0 = sQre[n][2 * w];    // wave-uniform broadcast b128
        const float4 re1 = sQre[n][2 * w + 1];
        const float4 im0 = sQim[n][2 * w];
        const float4 im1 = sQim[n][2 * w + 1];
        const v2f px = {p.x, p.x};
        const v2f py = {p.y, p.y};
        acc[0] = __builtin_elementwise_fma(px, (v2f){re0.x, re0.y},
                 __builtin_elementwise_fma(py, (v2f){im0.x, im0.y}, acc[0]));
        acc[1] = __builtin_elementwise_fma(px, (v2f){re0.z, re0.w},
                 __builtin_elementwise_fma(py, (v2f){im0.z, im0.w}, acc[1]));
        acc[2] = __builtin_elementwise_fma(px, (v2f){re1.x, re1.y},
                 __builtin_elementwise_fma(py, (v2f){im1.x, im1.y}, acc[2]));
        acc[3] = __builtin_elementwise_fma(px, (v2f){re1.z, re1.w},
                 __builtin_elementwise_fma(py, (v2f){im1.z, im1.w}, acc[3]));
    }

    float* out = K + (size_t)h * L + chunk + b;
#pragma unroll
    for (int j = 0; j < 4; ++j) {
        const int a0 = 8 * w + 2 * j;
        const int l0 = chunk + 64 * a0 + b;
        if (l0 < L)      out[(size_t)64 * a0]        = acc[j].x;
        if (l0 + 64 < L) out[(size_t)64 * (a0 + 1)]  = acc[j].y;
    }
}

extern "C" void kernel_launch(void* const* d_in, const int* in_sizes, int n_in,
                              void* d_out, int out_size, void* d_ws, size_t ws_size,
                              hipStream_t stream) {
    // inputs: [0]=L (scalar), [1]=C (H,N2,2), [2]=log_dt (H,),
    //         [3]=log_A_real (H,N2), [4]=A_imag (H,N2)
    const float* C          = (const float*)d_in[1];
    const float* log_dt     = (const float*)d_in[2];
    const float* log_A_real = (const float*)d_in[3];
    const float* A_imag     = (const float*)d_in[4];
    float* K = (float*)d_out;

    const int H = in_sizes[2];            // log_dt has H elements
    const int L = out_size / H;           // output is (H, L)
    const int chunks_per_h = (L + CHUNK - 1) / CHUNK;

    dim3 grid(H * chunks_per_h);
    dim3 block(BLOCK);
    s4d_vand_kernel<<<grid, block, 0, stream>>>(C, log_dt, log_A_real, A_imag,
                                                K, L, chunks_per_h);
}

// Round 7
// 13.548 us; speedup vs baseline: 3.3012x; 1.0234x over previous
//
#include <hip/hip_runtime.h>
#include <math.h>

#define N2V 32
#define BLOCK 512             // one block per h: 8 waves
#define CHUNK 4096            // 64 b-values x 64 a-values

typedef float v2f __attribute__((ext_vector_type(2)));

__global__ __launch_bounds__(BLOCK) void s4d_vand_kernel(
    const float* __restrict__ C,          // (H, N2, 2)
    const float* __restrict__ log_dt,     // (H,)
    const float* __restrict__ log_A_real, // (H, N2)
    const float* __restrict__ A_imag,     // (H, N2)
    float* __restrict__ K,                // (H, L)
    int L, int chunks_per_h)
{
    __shared__ float4 sC[N2V];            // (x, y, 2*Ceff_r, 2*Ceff_i)
    __shared__ float2 sP[N2V][64];        // P[n][b] = 2*Ceff_n * r_n^b
    __shared__ float4 sQre[N2V][16];      // Re r^(chunk+64a), a = 4k..4k+3
    __shared__ float4 sQim[N2V][16];      // -Im r^(chunk+64a)

    const int h     = blockIdx.x / chunks_per_h;
    const int chunk = (blockIdx.x % chunks_per_h) * CHUNK;
    const int t     = threadIdx.x;

    // ---- stage 1: per-n constants (accurate math, one-time) ----
    if (t < N2V) {
        const int n = t;
        const float dt = expf(log_dt[h]);
        const float ar = -expf(log_A_real[h * N2V + n]);  // Re(A)
        const float ai = A_imag[h * N2V + n];             // Im(A)
        const float x = ar * dt;                          // Re(dtA)
        const float y = ai * dt;                          // Im(dtA)
        float sn, cs;
        sincosf(y, &sn, &cs);
        const float e  = expf(x);
        const float wr = e * cs - 1.0f;                   // w = exp(dtA)-1
        const float wi = e * sn;
        const float inv = 1.0f / (ar * ar + ai * ai);     // w/A = w*conj(A)/|A|^2
        const float dr = (wr * ar + wi * ai) * inv;
        const float di = (wi * ar - wr * ai) * inv;
        const float cr = C[(h * N2V + n) * 2 + 0];
        const float ci = C[(h * N2V + n) * 2 + 1];
        sC[n] = make_float4(x, y,
                            2.0f * (cr * dr - ci * di),
                            2.0f * (cr * di + ci * dr));
    }
    __syncthreads();

    // ---- stage 2a: build P table (2048 entries, 4 per thread) ----
#pragma unroll
    for (int i = 0; i < 4; ++i) {
        const int e = t + i * BLOCK;          // 0..2047
        const int n = e >> 6;
        const int b = e & 63;
        const float4 c = sC[n];
        const float fb = (float)b;
        float sn, cs;
        __sincosf(c.y * fb, &sn, &cs);
        const float ex = __expf(c.x * fb);
        sP[n][b] = make_float2(ex * (c.z * cs - c.w * sn),
                               ex * (c.z * sn + c.w * cs));
    }
    // ---- stage 2b: build Q tables (512 float4-pairs, 1 per thread) ----
    {
        const int n = t >> 4;                 // 0..31
        const int k = t & 15;                 // 0..15 -> a = 4k..4k+3
        const float4 c = sC[n];
        float re[4], im[4];
#pragma unroll
        for (int j = 0; j < 4; ++j) {
            const float fl = (float)(chunk + 64 * (4 * k + j));
            float sn, cs;
            __sincosf(c.y * fl, &sn, &cs);
            const float ex = __expf(c.x * fl);
            re[j] = ex * cs;
            im[j] = -ex * sn;
        }
        sQre[n][k] = make_float4(re[0], re[1], re[2], re[3]);
        sQim[n][k] = make_float4(im[0], im[1], im[2], im[3]);
    }
    __syncthreads();

    // ---- main: packed-FMA reduction over n (identical to round 6) ----
    const int b = t & 63;                     // lane -> b (contiguous LDS + stores)
    const int w = t >> 6;                     // wave id -> a-group (a = 8w..8w+7)

    v2f acc[4];
#pragma unroll
    for (int j = 0; j < 4; ++j) acc[j] = (v2f){0.0f, 0.0f};

    // unroll 2 only: full unroll blew VGPR to 256 + spills in round 4.
#pragma unroll 2
    for (int n = 0; n < N2V; ++n) {
        const float2 p   = sP[n][b];          // per-lane b64, conflict-free
        const float4 re0 = sQre[n][2 * w];    // wave-uniform broadcast b128
        const float4 re1 = sQre[n][2 * w + 1];
        const float4 im0 = sQim[n][2 * w];
        const float4 im1 = sQim[n][2 * w + 1];
        const v2f px = {p.x, p.x};
        const v2f py = {p.y, p.y};
        acc[0] = __builtin_elementwise_fma(px, (v2f){re0.x, re0.y},
                 __builtin_elementwise_fma(py, (v2f){im0.x, im0.y}, acc[0]));
        acc[1] = __builtin_elementwise_fma(px, (v2f){re0.z, re0.w},
                 __builtin_elementwise_fma(py, (v2f){im0.z, im0.w}, acc[1]));
        acc[2] = __builtin_elementwise_fma(px, (v2f){re1.x, re1.y},
                 __builtin_elementwise_fma(py, (v2f){im1.x, im1.y}, acc[2]));
        acc[3] = __builtin_elementwise_fma(px, (v2f){re1.z, re1.w},
                 __builtin_elementwise_fma(py, (v2f){im1.z, im1.w}, acc[3]));
    }

    float* out = K + (size_t)h * L + chunk + b;
#pragma unroll
    for (int j = 0; j < 4; ++j) {
        const int a0 = 8 * w + 2 * j;
        const int l0 = chunk + 64 * a0 + b;
        if (l0 < L)      out[(size_t)64 * a0]       = acc[j].x;
        if (l0 + 64 < L) out[(size_t)64 * (a0 + 1)] = acc[j].y;
    }
}

extern "C" void kernel_launch(void* const* d_in, const int* in_sizes, int n_in,
                              void* d_out, int out_size, void* d_ws, size_t ws_size,
                              hipStream_t stream) {
    // inputs: [0]=L (scalar), [1]=C (H,N2,2), [2]=log_dt (H,),
    //         [3]=log_A_real (H,N2), [4]=A_imag (H,N2)
    const float* C          = (const float*)d_in[1];
    const float* log_dt     = (const float*)d_in[2];
    const float* log_A_real = (const float*)d_in[3];
    const float* A_imag     = (const float*)d_in[4];
    float* K = (float*)d_out;

    const int H = in_sizes[2];            // log_dt has H elements
    const int L = out_size / H;           // output is (H, L)
    const int chunks_per_h = (L + CHUNK - 1) / CHUNK;

    dim3 grid(H * chunks_per_h);
    dim3 block(BLOCK);
    s4d_vand_kernel<<<grid, block, 0, stream>>>(C, log_dt, log_A_real, A_imag,
                                                K, L, chunks_per_h);
}